// Round 11
// baseline (1736.172 us; speedup 1.0000x reference)
//
#include <hip/hip_runtime.h>
#include <math.h>

#define WIDTH 256
#define PTS 16
#define NROW 80            // 5 chains * 16 points
#define CPLANE 20480       // halves per component plane: 5v * 8kc * 64lane * 8
#define WT2_HALVES (5 * 2 * 65536)
#define GLO_GRID 768       // 3 blocks/CU; lo-slot = blockIdx (no aliasing)

typedef _Float16 f16x8 __attribute__((ext_vector_type(8)));
typedef _Float16 f16x4 __attribute__((ext_vector_type(4)));
typedef __fp16   h16x2 __attribute__((ext_vector_type(2)));   // cvt_pkrtz return type
typedef float    f32x4 __attribute__((ext_vector_type(4)));

__device__ __forceinline__ void split2(float f, _Float16& h, _Float16& l) {
    h = (_Float16)f;
    l = (_Float16)(f - (float)h);
}
// z=tanh(u), s=1-z^2 = 4t/(1+t)^2 with t=exp(-2|u|): no cancellation in saturation
__device__ __forceinline__ void tanh_s(float u, float& z, float& s) {
    const float t = __expf(-2.0f * fabsf(u));
    const float r = 1.0f / (1.0f + t);
    const float zm = (1.0f - t) * r;
    z = copysignf(zm, u);
    s = 4.0f * t * r * r;
}

// Pre-split w1..w5 into fp16 hi/lo, transposed + packed in MFMA A-frag order.
__global__ void prep_w_kernel(const float* __restrict__ w1, const float* __restrict__ w2,
                              const float* __restrict__ w3, const float* __restrict__ w4,
                              const float* __restrict__ w5, _Float16* __restrict__ wt2)
{
    const int idx = blockIdx.x * blockDim.x + threadIdx.x;
    if (idx >= 5 * 16 * 8 * 64) return;
    const int lane = idx & 63;
    const int kc   = (idx >> 6) & 7;
    const int jt   = (idx >> 9) & 15;
    const int l    = idx >> 13;
    const float* Wsrc[5] = { w1, w2, w3, w4, w5 };
    const float* W = Wsrc[l];
    const int j  = jt * 16 + (lane & 15);
    const int k0 = kc * 32 + (lane >> 4) * 8;
    f16x8 vh, vl;
    #pragma unroll
    for (int i = 0; i < 8; ++i) {
        _Float16 h, lo;
        split2(W[(k0 + i) * WIDTH + j], h, lo);
        vh[i] = h; vl[i] = lo;
    }
    const int fo = ((jt * 8 + kc) * 64 + lane) * 8;
    *(f16x8*)(wt2 + (l * 2 + 0) * 65536 + fo) = vh;
    *(f16x8*)(wt2 + (l * 2 + 1) * 65536 + fo) = vl;
}

// GLO=true: lo plane in global scratch (LDS=40960 -> 3 blocks/CU).
// GLO=false: lo plane in LDS (R10 structure, fallback).
template<bool GLO>
__global__ __launch_bounds__(256, GLO ? 3 : 2)
void pde_mfma_kernel(const float* __restrict__ xyt,
                     const float* __restrict__ w0, const float* __restrict__ b0,
                     const float* __restrict__ b1, const float* __restrict__ b2,
                     const float* __restrict__ b3, const float* __restrict__ b4,
                     const float* __restrict__ b5,
                     const float* __restrict__ w6, const float* __restrict__ b6,
                     const _Float16* __restrict__ wt2,
                     _Float16* __restrict__ losc,
                     float* __restrict__ out, int ntiles)
{
    __shared__ _Float16 Zs[GLO ? CPLANE : 2 * CPLANE];
    float* redf = (float*)Zs;
    _Float16* ZloG = losc + (size_t)blockIdx.x * CPLANE;   // used only if GLO

    const int tid = threadIdx.x;
    const int lane = tid & 63;
    const int wv   = tid >> 6;
    const int q    = lane >> 4;
    const int n15  = lane & 15;
    const float* Bsl[5] = { b1, b2, b3, b4, b5 };

    auto loR = [&](int off) -> f16x8 {
        if constexpr (GLO) return *(const f16x8*)(ZloG + off);
        else               return *(const f16x8*)&Zs[CPLANE + off];
    };
    auto loW8 = [&](int off, f16x8 v) {
        if constexpr (GLO) *(f16x8*)(ZloG + off) = v;
        else               *(f16x8*)&Zs[CPLANE + off] = v;
    };
    auto loW4 = [&](int off, f16x4 v) {
        if constexpr (GLO) *(f16x4*)(ZloG + off) = v;
        else               *(f16x4*)&Zs[CPLANE + off] = v;
    };

    for (int tile = blockIdx.x; tile < ntiles; tile += gridDim.x) {
        const long gp0 = (long)tile * PTS;

        // ---------------- layer 0: (3 -> 256), Taylor-mode, fp32 VALU ----------
        {
            const int p = tid & 15;
            const float x = xyt[(gp0 + p) * 3 + 0];
            const float y = xyt[(gp0 + p) * 3 + 1];
            const float t = xyt[(gp0 + p) * 3 + 2];
            #pragma unroll
            for (int half = 0; half < 2; ++half) {
                const int jg = (tid >> 4) + half * 16;
                f16x8 vh[5], vl[5];
                #pragma unroll
                for (int c = 0; c < 8; ++c) {
                    const int j = jg * 8 + c;
                    const float wx = w0[0 * WIDTH + j];
                    const float wy = w0[1 * WIDTH + j];
                    const float wt = w0[2 * WIDTH + j];
                    float zv, s;
                    tanh_s(fmaf(x, wx, fmaf(y, wy, fmaf(t, wt, b0[j]))), zv, s);
                    const float vals[5] = { zv, s * wx, s * wy, s * wt,
                                            -2.0f * zv * s * (wx * wx + wy * wy) };
                    #pragma unroll
                    for (int v = 0; v < 5; ++v) {
                        _Float16 h, lo;
                        split2(vals[v], h, lo);
                        vh[v][c] = h; vl[v][c] = lo;
                    }
                }
                #pragma unroll
                for (int v = 0; v < 5; ++v) {
                    const int off = ((v * 8 + (jg >> 2)) * 64 + (jg & 3) * 16 + p) * 8;
                    *(f16x8*)&Zs[off] = vh[v];
                    loW8(off, vl[v]);
                }
            }
        }
        __syncthreads();

        // ---------------- hidden layers 1..5: MFMA fp16 2-split (3 products) ----
        for (int l = 0; l < 5; ++l) {
            const _Float16* Wl = wt2 + l * 2 * 65536;
            f32x4 acc[5][4];
            #pragma unroll
            for (int v = 0; v < 5; ++v)
                #pragma unroll
                for (int Mt = 0; Mt < 4; ++Mt)
                    acc[v][Mt] = (f32x4){0.f, 0.f, 0.f, 0.f};

            #pragma unroll 2
            for (int kc = 0; kc < 8; ++kc) {
                f16x8 Ah[4], Al[4];
                #pragma unroll
                for (int Mt = 0; Mt < 4; ++Mt) {
                    const int fo = (((wv * 4 + Mt) * 8 + kc) * 64 + lane) * 8;
                    Ah[Mt] = *(const f16x8*)(Wl + fo);
                    Al[Mt] = *(const f16x8*)(Wl + 65536 + fo);
                }
                #pragma unroll
                for (int v = 0; v < 5; ++v) {
                    const int zo = ((v * 8 + kc) * 64 + lane) * 8;
                    const f16x8 Bh = *(const f16x8*)&Zs[zo];
                    const f16x8 Bl = loR(zo);
                    #pragma unroll
                    for (int Mt = 0; Mt < 4; ++Mt) {
                        f32x4 a = acc[v][Mt];
                        a = __builtin_amdgcn_mfma_f32_16x16x32_f16(Ah[Mt], Bl, a, 0, 0, 0);
                        a = __builtin_amdgcn_mfma_f32_16x16x32_f16(Al[Mt], Bh, a, 0, 0, 0);
                        a = __builtin_amdgcn_mfma_f32_16x16x32_f16(Ah[Mt], Bh, a, 0, 0, 0);
                        acc[v][Mt] = a;
                    }
                }
            }
            __syncthreads();   // all Z reads done before overwrite

            const float* Bb = Bsl[l];
            #pragma unroll
            for (int Mt = 0; Mt < 4; ++Mt) {
                const int jt = wv * 4 + Mt;
                float nv[5][4];
                #pragma unroll
                for (int reg = 0; reg < 4; ++reg) {
                    const int j = jt * 16 + q * 4 + reg;
                    float zv, s;
                    tanh_s(acc[0][Mt][reg] + Bb[j], zv, s);
                    const float u1 = acc[1][Mt][reg];
                    const float u2 = acc[2][Mt][reg];
                    nv[0][reg] = zv;
                    nv[1][reg] = s * u1;
                    nv[2][reg] = s * u2;
                    nv[3][reg] = s * acc[3][Mt][reg];
                    nv[4][reg] = fmaf(-2.0f * zv * s, fmaf(u1, u1, u2 * u2),
                                      s * acc[4][Mt][reg]);
                }
                const int j0 = jt * 16 + q * 4;
                const int off0 = ((j0 >> 5) * 64 + ((j0 >> 3) & 3) * 16 + n15) * 8 + (j0 & 7);
                #pragma unroll
                for (int v = 0; v < 5; ++v) {
                    const h16x2 h01 = __builtin_amdgcn_cvt_pkrtz(nv[v][0], nv[v][1]);
                    const h16x2 h23 = __builtin_amdgcn_cvt_pkrtz(nv[v][2], nv[v][3]);
                    const h16x2 l01 = __builtin_amdgcn_cvt_pkrtz(nv[v][0] - (float)h01[0],
                                                                 nv[v][1] - (float)h01[1]);
                    const h16x2 l23 = __builtin_amdgcn_cvt_pkrtz(nv[v][2] - (float)h23[0],
                                                                 nv[v][3] - (float)h23[1]);
                    *(f16x4*)&Zs[v * 4096 + off0] =
                        (f16x4){ (_Float16)h01[0], (_Float16)h01[1],
                                 (_Float16)h23[0], (_Float16)h23[1] };
                    loW4(v * 4096 + off0,
                        (f16x4){ (_Float16)l01[0], (_Float16)l01[1],
                                 (_Float16)l23[0], (_Float16)l23[1] });
                }
            }
            __syncthreads();
        }

        // ---------------- final layer: (256 -> 1) dot products ------------------
        float partial = 0.f;
        const int n    = tid >> 1;
        const int half = tid & 1;
        if (tid < 2 * NROW) {
            const int v = n >> 4, p = n & 15;
            for (int kk = half * 128; kk < half * 128 + 128; kk += 8) {
                const int off = ((v * 8 + (kk >> 5)) * 64 + ((kk >> 3) & 3) * 16 + p) * 8;
                const f16x8 zh = *(const f16x8*)&Zs[off];
                const f16x8 zl = loR(off);
                #pragma unroll
                for (int i = 0; i < 8; ++i)
                    partial = fmaf((float)zh[i] + (float)zl[i], w6[kk + i], partial);
            }
        }
        __syncthreads();                 // Z reads done before aliasing redf
        if (tid < 2 * NROW) redf[half * NROW + n] = partial;
        __syncthreads();
        if (tid < NROW) redf[2 * NROW + tid] = redf[tid] + redf[NROW + tid];
        __syncthreads();

        if (tid < PTS) {
            const int p = tid;
            const float* tot = redf + 2 * NROW;
            const float h   = tot[0 * 16 + p] + b6[0];
            const float hx  = tot[1 * 16 + p];
            const float hy  = tot[2 * 16 + p];
            const float ht  = tot[3 * 16 + p];
            const float lap = tot[4 * 16 + p];
            const float x = xyt[(gp0 + p) * 3 + 0];
            const float y = xyt[(gp0 + p) * 3 + 1];
            const float t = xyt[(gp0 + p) * 3 + 2];
            const float pi = 3.14159265358979323846f;
            const float f = sinf(pi * x) * sinf(pi * y) * expf(-t);
            out[gp0 + p] = ht - 0.5f * (fmaf(h, lap, fmaf(hx, hx, hy * hy))) - f;
        }
        __syncthreads();                 // redf reads done before next tile's layer0
    }
}

extern "C" void kernel_launch(void* const* d_in, const int* in_sizes, int n_in,
                              void* d_out, int out_size, void* d_ws, size_t ws_size,
                              hipStream_t stream) {
    const float* xyt = (const float*)d_in[0];
    const float* w0  = (const float*)d_in[1];
    const float* b0  = (const float*)d_in[2];
    const float* w1  = (const float*)d_in[3];
    const float* b1  = (const float*)d_in[4];
    const float* w2  = (const float*)d_in[5];
    const float* b2  = (const float*)d_in[6];
    const float* w3  = (const float*)d_in[7];
    const float* b3  = (const float*)d_in[8];
    const float* w4  = (const float*)d_in[9];
    const float* b4  = (const float*)d_in[10];
    const float* w5  = (const float*)d_in[11];
    const float* b5  = (const float*)d_in[12];
    const float* w6  = (const float*)d_in[13];
    const float* b6  = (const float*)d_in[14];
    float* out = (float*)d_out;

    _Float16* wt2  = (_Float16*)d_ws;                 // 1,310,720 B
    _Float16* losc = wt2 + WT2_HALVES;                // GLO_GRID * CPLANE halves

    const size_t need = (size_t)WT2_HALVES * 2 + (size_t)GLO_GRID * CPLANE * 2;
    const bool glo = ws_size >= need;

    prep_w_kernel<<<160, 256, 0, stream>>>(w1, w2, w3, w4, w5, wt2);

    const int npts = in_sizes[0] / 3;   // 131072
    const int ntiles = npts / PTS;      // 8192
    if (glo) {
        pde_mfma_kernel<true><<<GLO_GRID, 256, 0, stream>>>(
            xyt, w0, b0, b1, b2, b3, b4, b5, w6, b6, wt2, losc, out, ntiles);
    } else {
        pde_mfma_kernel<false><<<ntiles, 256, 0, stream>>>(
            xyt, w0, b0, b1, b2, b3, b4, b5, w6, b6, wt2, losc, out, ntiles);
    }
}

// Round 12
// 1201.505 us; speedup vs baseline: 1.4450x; 1.4450x over previous
//
#include <hip/hip_runtime.h>
#include <math.h>

#define WIDTH 256
#define PTS 16
#define NROW 80            // 5 chains * 16 points
#define CPLANE 20480       // halves per component plane: 5v * 8kc * 64lane * 8

typedef _Float16 f16x8 __attribute__((ext_vector_type(8)));
typedef _Float16 f16x4 __attribute__((ext_vector_type(4)));
typedef __fp16   h16x2 __attribute__((ext_vector_type(2)));   // cvt_pkrtz return type
typedef float    f32x4 __attribute__((ext_vector_type(4)));

// fp32 -> fp16 hi + fp16 lo (2-split, covers ~22-24 mantissa bits)
__device__ __forceinline__ void split2(float f, _Float16& h, _Float16& l) {
    h = (_Float16)f;
    l = (_Float16)(f - (float)h);
}
// z=tanh(u), s=1-z^2 = 4t/(1+t)^2 with t=exp(-2|u|): no cancellation in saturation
__device__ __forceinline__ void tanh_s(float u, float& z, float& s) {
    const float t = __expf(-2.0f * fabsf(u));
    const float r = 1.0f / (1.0f + t);
    const float zm = (1.0f - t) * r;
    z = copysignf(zm, u);
    s = 4.0f * t * r * r;
}

// Pre-split w1..w5 into fp16 hi/lo, transposed + packed in MFMA A-frag order:
// wt2[(l*2+c)*65536 + ((jt*8+kc)*64 + lane)*8 + i] = comp_c(W[k][j]),
// j = jt*16 + (lane&15), k = kc*32 + (lane>>4)*8 + i.
__global__ void prep_w_kernel(const float* __restrict__ w1, const float* __restrict__ w2,
                              const float* __restrict__ w3, const float* __restrict__ w4,
                              const float* __restrict__ w5, _Float16* __restrict__ wt2)
{
    const int idx = blockIdx.x * blockDim.x + threadIdx.x;
    if (idx >= 5 * 16 * 8 * 64) return;
    const int lane = idx & 63;
    const int kc   = (idx >> 6) & 7;
    const int jt   = (idx >> 9) & 15;
    const int l    = idx >> 13;
    const float* Wsrc[5] = { w1, w2, w3, w4, w5 };
    const float* W = Wsrc[l];
    const int j  = jt * 16 + (lane & 15);
    const int k0 = kc * 32 + (lane >> 4) * 8;
    f16x8 vh, vl;
    #pragma unroll
    for (int i = 0; i < 8; ++i) {
        _Float16 h, lo;
        split2(W[(k0 + i) * WIDTH + j], h, lo);
        vh[i] = h; vl[i] = lo;
    }
    const int fo = ((jt * 8 + kc) * 64 + lane) * 8;
    *(f16x8*)(wt2 + (l * 2 + 0) * 65536 + fo) = vh;
    *(f16x8*)(wt2 + (l * 2 + 1) * 65536 + fo) = vl;
}

// block = 512 threads (8 waves), 2 M-tiles per wave. LDS 81920 B -> 2 blocks/CU
// = 16 waves/CU = 4 waves/SIMD: phase diversity to overlap MFMA and VALU phases.
// __launch_bounds__(512,4): 4 waves/EU -> 2 blocks/CU, VGPR cap 128.
__global__ __launch_bounds__(512, 4)
void pde_mfma_kernel(const float* __restrict__ xyt,
                     const float* __restrict__ w0, const float* __restrict__ b0,
                     const float* __restrict__ b1, const float* __restrict__ b2,
                     const float* __restrict__ b3, const float* __restrict__ b4,
                     const float* __restrict__ b5,
                     const float* __restrict__ w6, const float* __restrict__ b6,
                     const _Float16* __restrict__ wt2,
                     float* __restrict__ out)
{
    // Z in B-frag consumption order: Zs[c*CPLANE + ((v*8+kc)*64 + lane)*8 + i]
    // holds Z[point n = lane&15, k = kc*32 + (lane>>4)*8 + i] of chain v.
    // k-loop reads are lane*16B contiguous -> conflict-free.
    __shared__ _Float16 Zs[2 * CPLANE];
    float* redf = (float*)Zs;         // aliased reduction scratch (after last Z read)

    const int tid = threadIdx.x;
    const long gp0 = (long)blockIdx.x * PTS;

    // ---------------- layer 0: (3 -> 256), Taylor-mode, fp32 VALU ----------
    // 512 threads = exact cover of 32 feature-groups x 16 points.
    {
        const int p  = tid & 15;
        const int jg = tid >> 4;            // 0..31, 8 features each
        const float x = xyt[(gp0 + p) * 3 + 0];
        const float y = xyt[(gp0 + p) * 3 + 1];
        const float t = xyt[(gp0 + p) * 3 + 2];
        f16x8 vh[5], vl[5];
        #pragma unroll
        for (int c = 0; c < 8; ++c) {
            const int j = jg * 8 + c;
            const float wx = w0[0 * WIDTH + j];
            const float wy = w0[1 * WIDTH + j];
            const float wt = w0[2 * WIDTH + j];
            float zv, s;
            tanh_s(fmaf(x, wx, fmaf(y, wy, fmaf(t, wt, b0[j]))), zv, s);
            const float vals[5] = { zv, s * wx, s * wy, s * wt,
                                    -2.0f * zv * s * (wx * wx + wy * wy) };
            #pragma unroll
            for (int v = 0; v < 5; ++v) {
                _Float16 h, lo;
                split2(vals[v], h, lo);
                vh[v][c] = h; vl[v][c] = lo;
            }
        }
        // j block jg*8..+7: kc = jg>>2, q' = jg&3, i = c
        #pragma unroll
        for (int v = 0; v < 5; ++v) {
            const int off = ((v * 8 + (jg >> 2)) * 64 + (jg & 3) * 16 + p) * 8;
            *(f16x8*)&Zs[0 * CPLANE + off] = vh[v];
            *(f16x8*)&Zs[1 * CPLANE + off] = vl[v];
        }
    }
    __syncthreads();

    // ---------------- hidden layers 1..5: MFMA fp16 2-split (3 products) ----
    const float* Bsl[5] = { b1, b2, b3, b4, b5 };
    const int lane = tid & 63;
    const int wv   = tid >> 6;       // wave 0..7 -> M-tiles {2w, 2w+1}
    const int q    = lane >> 4;
    const int n15  = lane & 15;

    for (int l = 0; l < 5; ++l) {
        const _Float16* Wl = wt2 + l * 2 * 65536;
        f32x4 acc[5][2];
        #pragma unroll
        for (int v = 0; v < 5; ++v)
            #pragma unroll
            for (int Mt = 0; Mt < 2; ++Mt)
                acc[v][Mt] = (f32x4){0.f, 0.f, 0.f, 0.f};

        #pragma unroll 2
        for (int kc = 0; kc < 8; ++kc) {
            f16x8 Ah[2], Al[2];
            #pragma unroll
            for (int Mt = 0; Mt < 2; ++Mt) {
                const int fo = (((wv * 2 + Mt) * 8 + kc) * 64 + lane) * 8;
                Ah[Mt] = *(const f16x8*)(Wl + fo);
                Al[Mt] = *(const f16x8*)(Wl + 65536 + fo);
            }
            #pragma unroll
            for (int v = 0; v < 5; ++v) {
                const int zo = ((v * 8 + kc) * 64 + lane) * 8;
                const f16x8 Bh = *(const f16x8*)&Zs[0 * CPLANE + zo];
                const f16x8 Bl = *(const f16x8*)&Zs[1 * CPLANE + zo];
                #pragma unroll
                for (int Mt = 0; Mt < 2; ++Mt) {
                    f32x4 a = acc[v][Mt];
                    a = __builtin_amdgcn_mfma_f32_16x16x32_f16(Ah[Mt], Bl, a, 0, 0, 0);
                    a = __builtin_amdgcn_mfma_f32_16x16x32_f16(Al[Mt], Bh, a, 0, 0, 0);
                    a = __builtin_amdgcn_mfma_f32_16x16x32_f16(Ah[Mt], Bh, a, 0, 0, 0);
                    acc[v][Mt] = a;
                }
            }
        }
        __syncthreads();   // all Zs reads done before overwrite

        // epilogue: lane holds (j = jt*16 + q*4 + reg, p = n15), all 5 chains
        const float* Bb = Bsl[l];
        #pragma unroll
        for (int Mt = 0; Mt < 2; ++Mt) {
            const int jt = wv * 2 + Mt;
            float nv[5][4];
            #pragma unroll
            for (int reg = 0; reg < 4; ++reg) {
                const int j = jt * 16 + q * 4 + reg;
                float zv, s;
                tanh_s(acc[0][Mt][reg] + Bb[j], zv, s);
                const float u1 = acc[1][Mt][reg];
                const float u2 = acc[2][Mt][reg];
                nv[0][reg] = zv;
                nv[1][reg] = s * u1;
                nv[2][reg] = s * u2;
                nv[3][reg] = s * acc[3][Mt][reg];
                nv[4][reg] = fmaf(-2.0f * zv * s, fmaf(u1, u1, u2 * u2),
                                  s * acc[4][Mt][reg]);
            }
            // j0 = jt*16 + q*4 -> kc' = j0>>5, q'' = (j0>>3)&3, i0 = j0&7
            const int j0 = jt * 16 + q * 4;
            const int off0 = ((j0 >> 5) * 64 + ((j0 >> 3) & 3) * 16 + n15) * 8 + (j0 & 7);
            #pragma unroll
            for (int v = 0; v < 5; ++v) {
                const h16x2 h01 = __builtin_amdgcn_cvt_pkrtz(nv[v][0], nv[v][1]);
                const h16x2 h23 = __builtin_amdgcn_cvt_pkrtz(nv[v][2], nv[v][3]);
                const h16x2 l01 = __builtin_amdgcn_cvt_pkrtz(nv[v][0] - (float)h01[0],
                                                             nv[v][1] - (float)h01[1]);
                const h16x2 l23 = __builtin_amdgcn_cvt_pkrtz(nv[v][2] - (float)h23[0],
                                                             nv[v][3] - (float)h23[1]);
                *(f16x4*)&Zs[0 * CPLANE + v * 4096 + off0] =
                    (f16x4){ (_Float16)h01[0], (_Float16)h01[1],
                             (_Float16)h23[0], (_Float16)h23[1] };
                *(f16x4*)&Zs[1 * CPLANE + v * 4096 + off0] =
                    (f16x4){ (_Float16)l01[0], (_Float16)l01[1],
                             (_Float16)l23[0], (_Float16)l23[1] };
            }
        }
        __syncthreads();
    }

    // ---------------- final layer: (256 -> 1) dot products ------------------
    // 80 rows x 4 chunks of 64 features; 320 active threads.
    float partial = 0.f;
    const int n  = tid >> 2;          // row 0..79 (valid if tid < 320)
    const int ch = tid & 3;           // feature chunk
    if (tid < 4 * NROW) {
        const int v = n >> 4, p = n & 15;
        for (int kk = ch * 64; kk < ch * 64 + 64; kk += 8) {
            const int off = ((v * 8 + (kk >> 5)) * 64 + ((kk >> 3) & 3) * 16 + p) * 8;
            const f16x8 zh = *(const f16x8*)&Zs[0 * CPLANE + off];
            const f16x8 zl = *(const f16x8*)&Zs[1 * CPLANE + off];
            #pragma unroll
            for (int i = 0; i < 8; ++i)
                partial = fmaf((float)zh[i] + (float)zl[i], w6[kk + i], partial);
        }
    }
    __syncthreads();                 // all reads of Zs done before aliasing
    if (tid < 4 * NROW) redf[ch * NROW + n] = partial;
    __syncthreads();
    if (tid < NROW)
        redf[4 * NROW + tid] = redf[tid] + redf[NROW + tid] +
                               redf[2 * NROW + tid] + redf[3 * NROW + tid];
    __syncthreads();

    // ---------------- residual ----------------
    if (tid < PTS) {
        const int p = tid;
        const float* tot = redf + 4 * NROW;
        const float h   = tot[0 * 16 + p] + b6[0];
        const float hx  = tot[1 * 16 + p];
        const float hy  = tot[2 * 16 + p];
        const float ht  = tot[3 * 16 + p];
        const float lap = tot[4 * 16 + p];
        const float x = xyt[(gp0 + p) * 3 + 0];
        const float y = xyt[(gp0 + p) * 3 + 1];
        const float t = xyt[(gp0 + p) * 3 + 2];
        const float pi = 3.14159265358979323846f;
        const float f = sinf(pi * x) * sinf(pi * y) * expf(-t);
        out[gp0 + p] = ht - 0.5f * (fmaf(h, lap, fmaf(hx, hx, hy * hy))) - f;
    }
}

extern "C" void kernel_launch(void* const* d_in, const int* in_sizes, int n_in,
                              void* d_out, int out_size, void* d_ws, size_t ws_size,
                              hipStream_t stream) {
    const float* xyt = (const float*)d_in[0];
    const float* w0  = (const float*)d_in[1];
    const float* b0  = (const float*)d_in[2];
    const float* w1  = (const float*)d_in[3];
    const float* b1  = (const float*)d_in[4];
    const float* w2  = (const float*)d_in[5];
    const float* b2  = (const float*)d_in[6];
    const float* w3  = (const float*)d_in[7];
    const float* b3  = (const float*)d_in[8];
    const float* w4  = (const float*)d_in[9];
    const float* b4  = (const float*)d_in[10];
    const float* w5  = (const float*)d_in[11];
    const float* b5  = (const float*)d_in[12];
    const float* w6  = (const float*)d_in[13];
    const float* b6  = (const float*)d_in[14];
    float* out = (float*)d_out;
    _Float16* wt2 = (_Float16*)d_ws;    // needs 5*2*65536*2 = 1,310,720 B

    prep_w_kernel<<<160, 256, 0, stream>>>(w1, w2, w3, w4, w5, wt2);

    const int npts = in_sizes[0] / 3;   // 131072
    dim3 grid(npts / PTS);              // 8192
    dim3 block(512);
    pde_mfma_kernel<<<grid, block, 0, stream>>>(xyt, w0, b0, b1, b2, b3, b4, b5,
                                                w6, b6, wt2, out);
}